// Round 1
// baseline (955.811 us; speedup 1.0000x reference)
//
#include <hip/hip_runtime.h>

#define T_TOK 12000
#define NSLOT 24000
#define DIN 2560
#define DH 512
#define DOUT 2048
#define NEXP 8

typedef unsigned short u16;
typedef unsigned int u32;
typedef __attribute__((ext_vector_type(4))) float f32x4;
typedef __attribute__((ext_vector_type(8))) short short8;
typedef __attribute__((ext_vector_type(4))) u16 u16x4;
typedef __attribute__((ext_vector_type(8))) u16 u16x8;

__device__ __forceinline__ u16 f2bf(float f) {
  u32 u = __builtin_bit_cast(u32, f);
  return (u16)((u + 0x7fffu + ((u >> 16) & 1u)) >> 16);
}
__device__ __forceinline__ float bf2f(u16 h) {
  return __builtin_bit_cast(float, (u32)h << 16);
}

__device__ __forceinline__ void gload_lds16(const void* g, void* l) {
  __builtin_amdgcn_global_load_lds((const __attribute__((address_space(1))) u32*)g,
                                   (__attribute__((address_space(3))) u32*)l, 16, 0, 0);
}

// ---------------- weight f32 -> bf16 ----------------
__global__ __launch_bounds__(256) void cvt_bf16_kernel(const float* __restrict__ in,
                                                       u16* __restrict__ out, int n4) {
  const int i = blockIdx.x * 256 + threadIdx.x;
  if (i >= n4) return;
  f32x4 v = ((const f32x4*)in)[i];
  u16x4 o = { f2bf(v.x), f2bf(v.y), f2bf(v.z), f2bf(v.w) };
  ((u16x4*)out)[i] = o;
}

// ---------------- fused pre-LN + router ----------------
// one block per token; 320 threads * 8 elems = 2560
__global__ __launch_bounds__(320) void ln_router_kernel(
    const float* __restrict__ x, const float* __restrict__ gamma, const float* __restrict__ beta,
    const float* __restrict__ rw, const float* __restrict__ rb,
    u16* __restrict__ nx, int* __restrict__ tok_e, float* __restrict__ tok_w,
    int* __restrict__ count) {
  const int t = blockIdx.x;
  const int tid = threadIdx.x;
  const int lane = tid & 63;
  const int wv = tid >> 6;
  const float* xrow = x + (size_t)t * DIN;
  f32x4 xa = ((const f32x4*)xrow)[tid];
  f32x4 xb = ((const f32x4*)xrow)[tid + 320];
  float s = xa.x + xa.y + xa.z + xa.w + xb.x + xb.y + xb.z + xb.w;
  float s2 = xa.x * xa.x + xa.y * xa.y + xa.z * xa.z + xa.w * xa.w +
             xb.x * xb.x + xb.y * xb.y + xb.z * xb.z + xb.w * xb.w;
#pragma unroll
  for (int off = 32; off > 0; off >>= 1) {
    s += __shfl_xor(s, off);
    s2 += __shfl_xor(s2, off);
  }
  __shared__ float red[5][2];
  __shared__ float redl[5][NEXP];
  if (lane == 0) { red[wv][0] = s; red[wv][1] = s2; }
  __syncthreads();
  float S = 0.f, S2 = 0.f;
#pragma unroll
  for (int w = 0; w < 5; ++w) { S += red[w][0]; S2 += red[w][1]; }
  const float mean = S * (1.0f / DIN);
  const float var = S2 * (1.0f / DIN) - mean * mean;
  const float rstd = rsqrtf(var + 1e-6f);
  f32x4 ga = ((const f32x4*)gamma)[tid], gb = ((const f32x4*)gamma)[tid + 320];
  f32x4 ba = ((const f32x4*)beta)[tid],  bb = ((const f32x4*)beta)[tid + 320];
  f32x4 nva = (xa - mean) * rstd * ga + ba;
  f32x4 nvb = (xb - mean) * rstd * gb + bb;
  u16* nxrow = nx + (size_t)t * DIN;
  u16x4 pa = { f2bf(nva.x), f2bf(nva.y), f2bf(nva.z), f2bf(nva.w) };
  u16x4 pb = { f2bf(nvb.x), f2bf(nvb.y), f2bf(nvb.z), f2bf(nvb.w) };
  ((u16x4*)nxrow)[tid] = pa;
  ((u16x4*)nxrow)[tid + 320] = pb;
  // router logits in fp32 (selection must match fp32 reference)
  float lp[NEXP];
#pragma unroll
  for (int e = 0; e < NEXP; ++e) {
    const float* rwe = rw + e * DIN;
    f32x4 ra = ((const f32x4*)rwe)[tid];
    f32x4 rb4 = ((const f32x4*)rwe)[tid + 320];
    lp[e] = nva.x * ra.x + nva.y * ra.y + nva.z * ra.z + nva.w * ra.w +
            nvb.x * rb4.x + nvb.y * rb4.y + nvb.z * rb4.z + nvb.w * rb4.w;
  }
#pragma unroll
  for (int e = 0; e < NEXP; ++e)
#pragma unroll
    for (int off = 32; off > 0; off >>= 1) lp[e] += __shfl_xor(lp[e], off);
  if (lane == 0) {
#pragma unroll
    for (int e = 0; e < NEXP; ++e) redl[wv][e] = lp[e];
  }
  __syncthreads();
  if (tid == 0) {
    float lg[NEXP];
#pragma unroll
    for (int e = 0; e < NEXP; ++e)
      lg[e] = redl[0][e] + redl[1][e] + redl[2][e] + redl[3][e] + redl[4][e] + rb[e];
    float mx = lg[0];
#pragma unroll
    for (int e = 1; e < NEXP; ++e) mx = fmaxf(mx, lg[e]);
    float p[NEXP], ps = 0.f;
#pragma unroll
    for (int e = 0; e < NEXP; ++e) { p[e] = expf(lg[e] - mx); ps += p[e]; }
    int i0 = 0;
#pragma unroll
    for (int e = 1; e < NEXP; ++e) if (p[e] > p[i0]) i0 = e;
    int i1 = (i0 == 0) ? 1 : 0;
#pragma unroll
    for (int e = 0; e < NEXP; ++e) if (e != i0 && p[e] > p[i1]) i1 = e;
    float w0 = p[i0] / ps, w1 = p[i1] / ps;
    const float inv = 1.0f / (w0 + w1 + 1e-20f);
    w0 *= inv; w1 *= inv;
    tok_e[2 * t] = i0; tok_e[2 * t + 1] = i1;
    tok_w[2 * t] = w0; tok_w[2 * t + 1] = w1;
    atomicAdd(&count[i0], 1);
    atomicAdd(&count[i1], 1);
  }
}

__global__ void prefix_kernel(const int* __restrict__ count, int* __restrict__ prefix) {
  if (threadIdx.x == 0) {
    int acc = 0;
    for (int e = 0; e < NEXP; ++e) { prefix[e] = acc; acc += count[e]; }
  }
}

__global__ __launch_bounds__(256) void assign_kernel(
    const int* __restrict__ tok_e, const float* __restrict__ tok_w, const int* __restrict__ prefix,
    int* __restrict__ cursor, int* __restrict__ slot_token, float* __restrict__ slot_w,
    int* __restrict__ token_slot) {
  const int t = blockIdx.x * 256 + threadIdx.x;
  if (t >= T_TOK) return;
#pragma unroll
  for (int k = 0; k < 2; ++k) {
    const int e = tok_e[2 * t + k];
    const int pos = atomicAdd(&cursor[e], 1);
    const int sl = prefix[e] + pos;
    slot_token[sl] = t;
    slot_w[sl] = tok_w[2 * t + k];
    token_slot[2 * t + k] = sl;
  }
}

// ---------------- GEMM (C[m,n] = sum_k A[m,k]*B[n,k]), bf16 in, bf16 out ----
// MODE 0: plain rows (M given).  MODE 1: gather A rows via slot_token, per-expert B/count.
// MODE 2: contiguous slot rows, per-expert B/count, per-row scale on store.
template <int MODE>
__global__ __launch_bounds__(256, 2) void gemm_bt(
    const u16* __restrict__ A, const u16* __restrict__ Bw, u16* __restrict__ C,
    int M, int N, int K,
    const int* __restrict__ counts, const int* __restrict__ prefix,
    const int* __restrict__ slot_token, const float* __restrict__ slot_w) {
  __shared__ u16 ldsA[128 * 64];
  __shared__ u16 ldsB[128 * 64];

  int m_valid, row_off;
  if constexpr (MODE == 0) {
    m_valid = M; row_off = 0;
  } else {
    const int cnt = counts[blockIdx.z];
    if ((int)blockIdx.y * 128 >= cnt) return;
    m_valid = cnt; row_off = prefix[blockIdx.z];
  }
  const u16* Bb = (MODE == 0) ? Bw : Bw + (size_t)blockIdx.z * N * K;

  const int tid = threadIdx.x;
  const int lane = tid & 63;
  const int wid = tid >> 6;
  const int kseg = (lane & 7) * 8;

  const u16* aptr[4];
  const u16* bptr[4];
#pragma unroll
  for (int i = 0; i < 4; ++i) {
    const int r = wid * 32 + i * 8 + (lane >> 3);
    int gr = blockIdx.y * 128 + r;
    gr = gr < m_valid ? gr : (m_valid - 1);
    if constexpr (MODE == 0)      aptr[i] = A + (size_t)gr * K;
    else if constexpr (MODE == 1) aptr[i] = A + (size_t)slot_token[row_off + gr] * K;
    else                          aptr[i] = A + (size_t)(row_off + gr) * K;
    bptr[i] = Bb + (size_t)(blockIdx.x * 128 + r) * K;
  }

  const f32x4 zero = {0.f, 0.f, 0.f, 0.f};
  f32x4 acc[4][4];
#pragma unroll
  for (int m = 0; m < 4; ++m)
#pragma unroll
    for (int n = 0; n < 4; ++n) acc[m][n] = zero;

  const int wr = (wid >> 1) * 64;
  const int wc = (wid & 1) * 64;
  const int fr = lane & 15;
  const int fk = (lane >> 4) * 8;

  for (int k0 = 0; k0 < K; k0 += 64) {
#pragma unroll
    for (int i = 0; i < 4; ++i) {
      gload_lds16(aptr[i] + k0 + kseg, &ldsA[(wid * 4 + i) * 512]);
      gload_lds16(bptr[i] + k0 + kseg, &ldsB[(wid * 4 + i) * 512]);
    }
    __syncthreads();
#pragma unroll
    for (int kk = 0; kk < 2; ++kk) {
      short8 af[4], bfm[4];
      const int kb = kk * 32 + fk;
#pragma unroll
      for (int m = 0; m < 4; ++m)
        af[m] = *(const short8*)&ldsA[(wr + m * 16 + fr) * 64 + kb];
#pragma unroll
      for (int n = 0; n < 4; ++n)
        bfm[n] = *(const short8*)&ldsB[(wc + n * 16 + fr) * 64 + kb];
#pragma unroll
      for (int m = 0; m < 4; ++m)
#pragma unroll
        for (int n = 0; n < 4; ++n)
          acc[m][n] = __builtin_amdgcn_mfma_f32_16x16x32_bf16(af[m], bfm[n], acc[m][n], 0, 0, 0);
    }
    __syncthreads();
  }

  const int ccol = wc + (lane & 15);
#pragma unroll
  for (int m = 0; m < 4; ++m) {
#pragma unroll
    for (int i = 0; i < 4; ++i) {
      const int row = wr + m * 16 + (lane >> 4) * 4 + i;
      const int gr = blockIdx.y * 128 + row;
      if (gr < m_valid) {
        float wscale = 1.0f;
        if constexpr (MODE == 2) wscale = slot_w[row_off + gr];
        u16* crow = C + (size_t)(row_off + gr) * N + blockIdx.x * 128;
#pragma unroll
        for (int n = 0; n < 4; ++n) crow[ccol + n * 16] = f2bf(acc[m][n][i] * wscale);
      }
    }
  }
}

// ---------------- SwiGLU activation: h[*,1024] -> a[*,512] ----------------
__global__ __launch_bounds__(256) void act_kernel(const u16* __restrict__ h,
                                                  u16* __restrict__ a, int rows) {
  const int idx = blockIdx.x * 256 + threadIdx.x;
  if (idx >= rows * 64) return;
  const int r = idx >> 6;
  const int c = (idx & 63) * 8;
  u16x8 g8 = *(const u16x8*)&h[(size_t)r * 1024 + c];
  u16x8 v8 = *(const u16x8*)&h[(size_t)r * 1024 + 512 + c];
  u16x8 o;
#pragma unroll
  for (int i = 0; i < 8; ++i) {
    const float g = bf2f(g8[i]);
    const float v = bf2f(v8[i]);
    const float sig = 1.0f / (1.0f + __expf(-g));
    o[i] = f2bf(g * sig * v);
  }
  *(u16x8*)&a[(size_t)r * 512 + c] = o;
}

// ---------------- final: out = LN(shared + eo[s0] + eo[s1]) ----------------
__global__ __launch_bounds__(256) void final_ln_kernel(
    const u16* __restrict__ sh, const u16* __restrict__ eo, const int* __restrict__ token_slot,
    const float* __restrict__ gamma, const float* __restrict__ beta, float* __restrict__ out) {
  const int t = blockIdx.x;
  const int tid = threadIdx.x;
  const int lane = tid & 63;
  const int wv = tid >> 6;
  const int s0 = token_slot[2 * t], s1 = token_slot[2 * t + 1];
  const int c = tid * 8;
  u16x8 a8 = *(const u16x8*)&sh[(size_t)t * DOUT + c];
  u16x8 b8 = *(const u16x8*)&eo[(size_t)s0 * DOUT + c];
  u16x8 c8 = *(const u16x8*)&eo[(size_t)s1 * DOUT + c];
  float v[8];
  float s = 0.f, s2 = 0.f;
#pragma unroll
  for (int i = 0; i < 8; ++i) {
    v[i] = bf2f(a8[i]) + bf2f(b8[i]) + bf2f(c8[i]);
    s += v[i];
    s2 += v[i] * v[i];
  }
#pragma unroll
  for (int off = 32; off > 0; off >>= 1) {
    s += __shfl_xor(s, off);
    s2 += __shfl_xor(s2, off);
  }
  __shared__ float red[4][2];
  if (lane == 0) { red[wv][0] = s; red[wv][1] = s2; }
  __syncthreads();
  const float S = red[0][0] + red[1][0] + red[2][0] + red[3][0];
  const float S2 = red[0][1] + red[1][1] + red[2][1] + red[3][1];
  const float mean = S * (1.0f / DOUT);
  const float var = S2 * (1.0f / DOUT) - mean * mean;
  const float rstd = rsqrtf(var + 1e-6f);
  f32x4 g0 = ((const f32x4*)gamma)[tid * 2], g1 = ((const f32x4*)gamma)[tid * 2 + 1];
  f32x4 be0 = ((const f32x4*)beta)[tid * 2], be1 = ((const f32x4*)beta)[tid * 2 + 1];
  f32x4 o0, o1;
#pragma unroll
  for (int i = 0; i < 4; ++i) {
    o0[i] = (v[i] - mean) * rstd * g0[i] + be0[i];
    o1[i] = (v[4 + i] - mean) * rstd * g1[i] + be1[i];
  }
  f32x4* orow = (f32x4*)(out + (size_t)t * DOUT);
  orow[tid * 2] = o0;
  orow[tid * 2 + 1] = o1;
}

extern "C" void kernel_launch(void* const* d_in, const int* in_sizes, int n_in,
                              void* d_out, int out_size, void* d_ws, size_t ws_size,
                              hipStream_t stream) {
  (void)in_sizes; (void)n_in; (void)out_size; (void)ws_size;
  const float* x = (const float*)d_in[0];
  const float* ln_pre_g = (const float*)d_in[1];
  const float* ln_pre_b = (const float*)d_in[2];
  const float* router_w = (const float*)d_in[3];
  const float* router_b = (const float*)d_in[4];
  const float* shared_w12 = (const float*)d_in[5];
  const float* shared_w3 = (const float*)d_in[6];
  const float* experts_w12 = (const float*)d_in[7];
  const float* experts_w3 = (const float*)d_in[8];
  const float* ln_post_g = (const float*)d_in[9];
  const float* ln_post_b = (const float*)d_in[10];
  float* out = (float*)d_out;

  size_t off = 0;
  char* ws = (char*)d_ws;
  auto take = [&](size_t bytes) -> void* {
    void* p = ws + off;
    off += (bytes + 255) & ~(size_t)255;
    return p;
  };
  u16* w12s = (u16*)take((size_t)1024 * 2560 * 2);
  u16* w3s  = (u16*)take((size_t)2048 * 512 * 2);
  u16* ew12 = (u16*)take((size_t)NEXP * 1024 * 2560 * 2);
  u16* ew3  = (u16*)take((size_t)NEXP * 2048 * 512 * 2);
  u16* nx   = (u16*)take((size_t)T_TOK * DIN * 2);
  u16* a_s  = (u16*)take((size_t)T_TOK * DH * 2);
  u16* a_e  = (u16*)take((size_t)NSLOT * DH * 2);
  u16* sh_o = (u16*)take((size_t)T_TOK * DOUT * 2);
  u16* eo   = (u16*)take((size_t)NSLOT * DOUT * 2);
  u16* h_s  = eo;                              // alias: dead before eo written
  u16* h_e  = eo + (size_t)T_TOK * 1024;       // alias: dead before eo written
  int* tok_e = (int*)take(NSLOT * 4);
  float* tok_w = (float*)take(NSLOT * 4);
  int* slot_token = (int*)take(NSLOT * 4);
  float* slot_w = (float*)take(NSLOT * 4);
  int* token_slot = (int*)take(NSLOT * 4);
  int* cnt = (int*)take(96);     // count[8] | prefix[8] | cursor[8]
  int* prefix = cnt + 8;
  int* cursor = cnt + 16;

  hipMemsetAsync(cnt, 0, 96, stream);

  cvt_bf16_kernel<<<(1024 * 2560 / 4 + 255) / 256, 256, 0, stream>>>(shared_w12, w12s, 1024 * 2560 / 4);
  cvt_bf16_kernel<<<(2048 * 512 / 4 + 255) / 256, 256, 0, stream>>>(shared_w3, w3s, 2048 * 512 / 4);
  cvt_bf16_kernel<<<(NEXP * 1024 * 2560 / 4 + 255) / 256, 256, 0, stream>>>(experts_w12, ew12, NEXP * 1024 * 2560 / 4);
  cvt_bf16_kernel<<<(NEXP * 2048 * 512 / 4 + 255) / 256, 256, 0, stream>>>(experts_w3, ew3, NEXP * 2048 * 512 / 4);

  ln_router_kernel<<<T_TOK, 320, 0, stream>>>(x, ln_pre_g, ln_pre_b, router_w, router_b,
                                              nx, tok_e, tok_w, cnt);
  prefix_kernel<<<1, 64, 0, stream>>>(cnt, prefix);
  assign_kernel<<<(T_TOK + 255) / 256, 256, 0, stream>>>(tok_e, tok_w, prefix, cursor,
                                                         slot_token, slot_w, token_slot);

  // shared FFN
  gemm_bt<0><<<dim3(8, 94, 1), 256, 0, stream>>>(nx, w12s, h_s, T_TOK, 1024, 2560,
                                                 nullptr, nullptr, nullptr, nullptr);
  act_kernel<<<3000, 256, 0, stream>>>(h_s, a_s, T_TOK);
  gemm_bt<0><<<dim3(16, 94, 1), 256, 0, stream>>>(a_s, w3s, sh_o, T_TOK, 2048, 512,
                                                  nullptr, nullptr, nullptr, nullptr);
  // expert FFNs (top-2 compacted slots)
  gemm_bt<1><<<dim3(8, 94, NEXP), 256, 0, stream>>>(nx, ew12, h_e, 0, 1024, 2560,
                                                    cnt, prefix, slot_token, nullptr);
  act_kernel<<<6000, 256, 0, stream>>>(h_e, a_e, NSLOT);
  gemm_bt<2><<<dim3(16, 94, NEXP), 256, 0, stream>>>(a_e, ew3, eo, 0, 2048, 512,
                                                     cnt, prefix, slot_token, slot_w);

  final_ln_kernel<<<T_TOK, 256, 0, stream>>>(sh_o, eo, token_slot, ln_post_g, ln_post_b, out);
}

// Round 2
// 713.744 us; speedup vs baseline: 1.3392x; 1.3392x over previous
//
#include <hip/hip_runtime.h>

#define T_TOK 12000
#define NSLOT 24000
#define DIN 2560
#define DH 512
#define DOUT 2048
#define NEXP 8

typedef unsigned short u16;
typedef unsigned int u32;
typedef __attribute__((ext_vector_type(4))) float f32x4;
typedef __attribute__((ext_vector_type(8))) short short8;
typedef __attribute__((ext_vector_type(4))) u16 u16x4;
typedef __attribute__((ext_vector_type(8))) u16 u16x8;

__device__ __forceinline__ u16 f2bf(float f) {
  u32 u = __builtin_bit_cast(u32, f);
  return (u16)((u + 0x7fffu + ((u >> 16) & 1u)) >> 16);
}
__device__ __forceinline__ float bf2f(u16 h) {
  return __builtin_bit_cast(float, (u32)h << 16);
}

__device__ __forceinline__ void gload_lds16(const void* g, void* l) {
  __builtin_amdgcn_global_load_lds((const __attribute__((address_space(1))) u32*)g,
                                   (__attribute__((address_space(3))) u32*)l, 16, 0, 0);
}

// ---------------- weight f32 -> bf16 ----------------
__global__ __launch_bounds__(256) void cvt_bf16_kernel(const float* __restrict__ in,
                                                       u16* __restrict__ out, int n4) {
  const int i = blockIdx.x * 256 + threadIdx.x;
  if (i >= n4) return;
  f32x4 v = ((const f32x4*)in)[i];
  u16x4 o = { f2bf(v.x), f2bf(v.y), f2bf(v.z), f2bf(v.w) };
  ((u16x4*)out)[i] = o;
}

// ---------------- fused pre-LN + router: ONE WAVE PER TOKEN ----------------
// 64 lanes x 10 f32x4 = 2560 elems; 4 tokens per 256-thread block.
__global__ __launch_bounds__(256) void ln_router_kernel(
    const float* __restrict__ x, const float* __restrict__ gamma, const float* __restrict__ beta,
    const float* __restrict__ rw, const float* __restrict__ rb,
    u16* __restrict__ nx, int* __restrict__ tok_e, float* __restrict__ tok_w,
    int* __restrict__ count) {
  const int t = blockIdx.x * 4 + (threadIdx.x >> 6);
  const int lane = threadIdx.x & 63;
  const f32x4* xrow = (const f32x4*)(x + (size_t)t * DIN);

  f32x4 xv[10];
  float s = 0.f, s2 = 0.f;
#pragma unroll
  for (int c = 0; c < 10; ++c) {
    xv[c] = xrow[c * 64 + lane];
#pragma unroll
    for (int i = 0; i < 4; ++i) { s += xv[c][i]; s2 += xv[c][i] * xv[c][i]; }
  }
#pragma unroll
  for (int off = 32; off > 0; off >>= 1) {
    s += __shfl_xor(s, off);
    s2 += __shfl_xor(s2, off);
  }
  const float mean = s * (1.0f / DIN);
  const float var = s2 * (1.0f / DIN) - mean * mean;
  const float rstd = rsqrtf(var + 1e-6f);

  u16* nxrow = nx + (size_t)t * DIN;
#pragma unroll
  for (int c = 0; c < 10; ++c) {
    f32x4 g = ((const f32x4*)gamma)[c * 64 + lane];
    f32x4 b = ((const f32x4*)beta)[c * 64 + lane];
    xv[c] = (xv[c] - mean) * rstd * g + b;   // xv now holds nx (f32)
    u16x4 p = { f2bf(xv[c].x), f2bf(xv[c].y), f2bf(xv[c].z), f2bf(xv[c].w) };
    ((u16x4*)nxrow)[c * 64 + lane] = p;
  }

  // router logits in fp32 (selection must match fp32 reference)
  float lp[NEXP];
#pragma unroll
  for (int e = 0; e < NEXP; ++e) {
    const f32x4* rwe = (const f32x4*)(rw + (size_t)e * DIN);
    float acc = 0.f;
#pragma unroll
    for (int c = 0; c < 10; ++c) {
      f32x4 r = rwe[c * 64 + lane];
      acc += xv[c].x * r.x + xv[c].y * r.y + xv[c].z * r.z + xv[c].w * r.w;
    }
    lp[e] = acc;
  }
#pragma unroll
  for (int e = 0; e < NEXP; ++e)
#pragma unroll
    for (int off = 32; off > 0; off >>= 1) lp[e] += __shfl_xor(lp[e], off);

  if (lane == 0) {
    float lg[NEXP];
#pragma unroll
    for (int e = 0; e < NEXP; ++e) lg[e] = lp[e] + rb[e];
    float mx = lg[0];
#pragma unroll
    for (int e = 1; e < NEXP; ++e) mx = fmaxf(mx, lg[e]);
    float p[NEXP], ps = 0.f;
#pragma unroll
    for (int e = 0; e < NEXP; ++e) { p[e] = expf(lg[e] - mx); ps += p[e]; }
    int i0 = 0;
#pragma unroll
    for (int e = 1; e < NEXP; ++e) if (p[e] > p[i0]) i0 = e;
    int i1 = (i0 == 0) ? 1 : 0;
#pragma unroll
    for (int e = 0; e < NEXP; ++e) if (e != i0 && p[e] > p[i1]) i1 = e;
    float w0 = p[i0] / ps, w1 = p[i1] / ps;
    const float inv = 1.0f / (w0 + w1 + 1e-20f);
    w0 *= inv; w1 *= inv;
    tok_e[2 * t] = i0; tok_e[2 * t + 1] = i1;
    tok_w[2 * t] = w0; tok_w[2 * t + 1] = w1;
    atomicAdd(&count[i0 * 32], 1);   // 1 counter per 128B line
    atomicAdd(&count[i1 * 32], 1);
  }
}

__global__ void prefix_kernel(const int* __restrict__ count, int* __restrict__ prefix) {
  if (threadIdx.x == 0) {
    int acc = 0;
    for (int e = 0; e < NEXP; ++e) { prefix[e] = acc; acc += count[e * 32]; }
  }
}

__global__ __launch_bounds__(256) void assign_kernel(
    const int* __restrict__ tok_e, const float* __restrict__ tok_w, const int* __restrict__ prefix,
    int* __restrict__ cursor, int* __restrict__ slot_token, float* __restrict__ slot_w,
    int* __restrict__ token_slot) {
  const int t = blockIdx.x * 256 + threadIdx.x;
  if (t >= T_TOK) return;
#pragma unroll
  for (int k = 0; k < 2; ++k) {
    const int e = tok_e[2 * t + k];
    const int pos = atomicAdd(&cursor[e * 32], 1);   // 1 cursor per 128B line
    const int sl = prefix[e] + pos;
    slot_token[sl] = t;
    slot_w[sl] = tok_w[2 * t + k];
    token_slot[2 * t + k] = sl;
  }
}

// ---------------- GEMM (C[m,n] = sum_k A[m,k]*B[n,k]), bf16 in, bf16 out ----
// MODE 0: plain rows (M given).  MODE 1: gather A rows via slot_token, per-expert B/count.
// MODE 2: contiguous slot rows, per-expert B/count, per-row scale on store.
template <int MODE>
__global__ __launch_bounds__(256, 2) void gemm_bt(
    const u16* __restrict__ A, const u16* __restrict__ Bw, u16* __restrict__ C,
    int M, int N, int K,
    const int* __restrict__ counts, const int* __restrict__ prefix,
    const int* __restrict__ slot_token, const float* __restrict__ slot_w) {
  __shared__ u16 ldsA[128 * 64];
  __shared__ u16 ldsB[128 * 64];

  int m_valid, row_off;
  if constexpr (MODE == 0) {
    m_valid = M; row_off = 0;
  } else {
    const int cnt = counts[blockIdx.z * 32];
    if ((int)blockIdx.y * 128 >= cnt) return;
    m_valid = cnt; row_off = prefix[blockIdx.z];
  }
  const u16* Bb = (MODE == 0) ? Bw : Bw + (size_t)blockIdx.z * N * K;

  const int tid = threadIdx.x;
  const int lane = tid & 63;
  const int wid = tid >> 6;
  const int kseg = (lane & 7) * 8;

  const u16* aptr[4];
  const u16* bptr[4];
#pragma unroll
  for (int i = 0; i < 4; ++i) {
    const int r = wid * 32 + i * 8 + (lane >> 3);
    int gr = blockIdx.y * 128 + r;
    gr = gr < m_valid ? gr : (m_valid - 1);
    if constexpr (MODE == 0)      aptr[i] = A + (size_t)gr * K;
    else if constexpr (MODE == 1) aptr[i] = A + (size_t)slot_token[row_off + gr] * K;
    else                          aptr[i] = A + (size_t)(row_off + gr) * K;
    bptr[i] = Bb + (size_t)(blockIdx.x * 128 + r) * K;
  }

  const f32x4 zero = {0.f, 0.f, 0.f, 0.f};
  f32x4 acc[4][4];
#pragma unroll
  for (int m = 0; m < 4; ++m)
#pragma unroll
    for (int n = 0; n < 4; ++n) acc[m][n] = zero;

  const int wr = (wid >> 1) * 64;
  const int wc = (wid & 1) * 64;
  const int fr = lane & 15;
  const int fk = (lane >> 4) * 8;

  for (int k0 = 0; k0 < K; k0 += 64) {
#pragma unroll
    for (int i = 0; i < 4; ++i) {
      gload_lds16(aptr[i] + k0 + kseg, &ldsA[(wid * 4 + i) * 512]);
      gload_lds16(bptr[i] + k0 + kseg, &ldsB[(wid * 4 + i) * 512]);
    }
    __syncthreads();
#pragma unroll
    for (int kk = 0; kk < 2; ++kk) {
      short8 af[4], bfm[4];
      const int kb = kk * 32 + fk;
#pragma unroll
      for (int m = 0; m < 4; ++m)
        af[m] = *(const short8*)&ldsA[(wr + m * 16 + fr) * 64 + kb];
#pragma unroll
      for (int n = 0; n < 4; ++n)
        bfm[n] = *(const short8*)&ldsB[(wc + n * 16 + fr) * 64 + kb];
#pragma unroll
      for (int m = 0; m < 4; ++m)
#pragma unroll
        for (int n = 0; n < 4; ++n)
          acc[m][n] = __builtin_amdgcn_mfma_f32_16x16x32_bf16(af[m], bfm[n], acc[m][n], 0, 0, 0);
    }
    __syncthreads();
  }

  const int ccol = wc + (lane & 15);
#pragma unroll
  for (int m = 0; m < 4; ++m) {
#pragma unroll
    for (int i = 0; i < 4; ++i) {
      const int row = wr + m * 16 + (lane >> 4) * 4 + i;
      const int gr = blockIdx.y * 128 + row;
      if (gr < m_valid) {
        float wscale = 1.0f;
        if constexpr (MODE == 2) wscale = slot_w[row_off + gr];
        u16* crow = C + (size_t)(row_off + gr) * N + blockIdx.x * 128;
#pragma unroll
        for (int n = 0; n < 4; ++n) crow[ccol + n * 16] = f2bf(acc[m][n][i] * wscale);
      }
    }
  }
}

// ---------------- SwiGLU activation: h[*,1024] -> a[*,512] ----------------
__global__ __launch_bounds__(256) void act_kernel(const u16* __restrict__ h,
                                                  u16* __restrict__ a, int rows) {
  const int idx = blockIdx.x * 256 + threadIdx.x;
  if (idx >= rows * 64) return;
  const int r = idx >> 6;
  const int c = (idx & 63) * 8;
  u16x8 g8 = *(const u16x8*)&h[(size_t)r * 1024 + c];
  u16x8 v8 = *(const u16x8*)&h[(size_t)r * 1024 + 512 + c];
  u16x8 o;
#pragma unroll
  for (int i = 0; i < 8; ++i) {
    const float g = bf2f(g8[i]);
    const float v = bf2f(v8[i]);
    const float sig = 1.0f / (1.0f + __expf(-g));
    o[i] = f2bf(g * sig * v);
  }
  *(u16x8*)&a[(size_t)r * 512 + c] = o;
}

// ---------------- final: out = LN(shared + eo[s0] + eo[s1]) ----------------
__global__ __launch_bounds__(256) void final_ln_kernel(
    const u16* __restrict__ sh, const u16* __restrict__ eo, const int* __restrict__ token_slot,
    const float* __restrict__ gamma, const float* __restrict__ beta, float* __restrict__ out) {
  const int t = blockIdx.x;
  const int tid = threadIdx.x;
  const int lane = tid & 63;
  const int wv = tid >> 6;
  const int s0 = token_slot[2 * t], s1 = token_slot[2 * t + 1];
  const int c = tid * 8;
  u16x8 a8 = *(const u16x8*)&sh[(size_t)t * DOUT + c];
  u16x8 b8 = *(const u16x8*)&eo[(size_t)s0 * DOUT + c];
  u16x8 c8 = *(const u16x8*)&eo[(size_t)s1 * DOUT + c];
  float v[8];
  float s = 0.f, s2 = 0.f;
#pragma unroll
  for (int i = 0; i < 8; ++i) {
    v[i] = bf2f(a8[i]) + bf2f(b8[i]) + bf2f(c8[i]);
    s += v[i];
    s2 += v[i] * v[i];
  }
#pragma unroll
  for (int off = 32; off > 0; off >>= 1) {
    s += __shfl_xor(s, off);
    s2 += __shfl_xor(s2, off);
  }
  __shared__ float red[4][2];
  if (lane == 0) { red[wv][0] = s; red[wv][1] = s2; }
  __syncthreads();
  const float S = red[0][0] + red[1][0] + red[2][0] + red[3][0];
  const float S2 = red[0][1] + red[1][1] + red[2][1] + red[3][1];
  const float mean = S * (1.0f / DOUT);
  const float var = S2 * (1.0f / DOUT) - mean * mean;
  const float rstd = rsqrtf(var + 1e-6f);
  f32x4 g0 = ((const f32x4*)gamma)[tid * 2], g1 = ((const f32x4*)gamma)[tid * 2 + 1];
  f32x4 be0 = ((const f32x4*)beta)[tid * 2], be1 = ((const f32x4*)beta)[tid * 2 + 1];
  f32x4 o0, o1;
#pragma unroll
  for (int i = 0; i < 4; ++i) {
    o0[i] = (v[i] - mean) * rstd * g0[i] + be0[i];
    o1[i] = (v[4 + i] - mean) * rstd * g1[i] + be1[i];
  }
  f32x4* orow = (f32x4*)(out + (size_t)t * DOUT);
  orow[tid * 2] = o0;
  orow[tid * 2 + 1] = o1;
}

extern "C" void kernel_launch(void* const* d_in, const int* in_sizes, int n_in,
                              void* d_out, int out_size, void* d_ws, size_t ws_size,
                              hipStream_t stream) {
  (void)in_sizes; (void)n_in; (void)out_size; (void)ws_size;
  const float* x = (const float*)d_in[0];
  const float* ln_pre_g = (const float*)d_in[1];
  const float* ln_pre_b = (const float*)d_in[2];
  const float* router_w = (const float*)d_in[3];
  const float* router_b = (const float*)d_in[4];
  const float* shared_w12 = (const float*)d_in[5];
  const float* shared_w3 = (const float*)d_in[6];
  const float* experts_w12 = (const float*)d_in[7];
  const float* experts_w3 = (const float*)d_in[8];
  const float* ln_post_g = (const float*)d_in[9];
  const float* ln_post_b = (const float*)d_in[10];
  float* out = (float*)d_out;

  size_t off = 0;
  char* ws = (char*)d_ws;
  auto take = [&](size_t bytes) -> void* {
    void* p = ws + off;
    off += (bytes + 255) & ~(size_t)255;
    return p;
  };
  u16* w12s = (u16*)take((size_t)1024 * 2560 * 2);
  u16* w3s  = (u16*)take((size_t)2048 * 512 * 2);
  u16* ew12 = (u16*)take((size_t)NEXP * 1024 * 2560 * 2);
  u16* ew3  = (u16*)take((size_t)NEXP * 2048 * 512 * 2);
  u16* nx   = (u16*)take((size_t)T_TOK * DIN * 2);
  u16* a_s  = (u16*)take((size_t)T_TOK * DH * 2);
  u16* a_e  = (u16*)take((size_t)NSLOT * DH * 2);
  u16* sh_o = (u16*)take((size_t)T_TOK * DOUT * 2);
  u16* eo   = (u16*)take((size_t)NSLOT * DOUT * 2);
  u16* h_s  = eo;                              // alias: dead before eo written
  u16* h_e  = eo + (size_t)T_TOK * 1024;       // alias: dead before eo written
  int* tok_e = (int*)take(NSLOT * 4);
  float* tok_w = (float*)take(NSLOT * 4);
  int* slot_token = (int*)take(NSLOT * 4);
  float* slot_w = (float*)take(NSLOT * 4);
  int* token_slot = (int*)take(NSLOT * 4);
  int* cnt = (int*)take(3 * 8 * 32 * 4);   // count[8*32] | cursor[8*32] | prefix[8]
  int* cursor = cnt + 8 * 32;
  int* prefix = cnt + 2 * 8 * 32;

  hipMemsetAsync(cnt, 0, 3 * 8 * 32 * 4, stream);

  cvt_bf16_kernel<<<(1024 * 2560 / 4 + 255) / 256, 256, 0, stream>>>(shared_w12, w12s, 1024 * 2560 / 4);
  cvt_bf16_kernel<<<(2048 * 512 / 4 + 255) / 256, 256, 0, stream>>>(shared_w3, w3s, 2048 * 512 / 4);
  cvt_bf16_kernel<<<(NEXP * 1024 * 2560 / 4 + 255) / 256, 256, 0, stream>>>(experts_w12, ew12, NEXP * 1024 * 2560 / 4);
  cvt_bf16_kernel<<<(NEXP * 2048 * 512 / 4 + 255) / 256, 256, 0, stream>>>(experts_w3, ew3, NEXP * 2048 * 512 / 4);

  ln_router_kernel<<<T_TOK / 4, 256, 0, stream>>>(x, ln_pre_g, ln_pre_b, router_w, router_b,
                                                  nx, tok_e, tok_w, cnt);
  prefix_kernel<<<1, 64, 0, stream>>>(cnt, prefix);
  assign_kernel<<<(T_TOK + 255) / 256, 256, 0, stream>>>(tok_e, tok_w, prefix, cursor,
                                                         slot_token, slot_w, token_slot);

  // shared FFN
  gemm_bt<0><<<dim3(8, 94, 1), 256, 0, stream>>>(nx, w12s, h_s, T_TOK, 1024, 2560,
                                                 nullptr, nullptr, nullptr, nullptr);
  act_kernel<<<3000, 256, 0, stream>>>(h_s, a_s, T_TOK);
  gemm_bt<0><<<dim3(16, 94, 1), 256, 0, stream>>>(a_s, w3s, sh_o, T_TOK, 2048, 512,
                                                  nullptr, nullptr, nullptr, nullptr);
  // expert FFNs (top-2 compacted slots)
  gemm_bt<1><<<dim3(8, 94, NEXP), 256, 0, stream>>>(nx, ew12, h_e, 0, 1024, 2560,
                                                    cnt, prefix, slot_token, nullptr);
  act_kernel<<<6000, 256, 0, stream>>>(h_e, a_e, NSLOT);
  gemm_bt<2><<<dim3(16, 94, NEXP), 256, 0, stream>>>(a_e, ew3, eo, 0, 2048, 512,
                                                     cnt, prefix, slot_token, slot_w);

  final_ln_kernel<<<T_TOK, 256, 0, stream>>>(sh_o, eo, token_slot, ln_post_g, ln_post_b, out);
}

// Round 3
// 647.075 us; speedup vs baseline: 1.4771x; 1.1030x over previous
//
#include <hip/hip_runtime.h>

#define T_TOK 12000
#define NSLOT 24000
#define DIN 2560
#define DH 512
#define DOUT 2048
#define NEXP 8
#define MSH 12000
#define SHBASE 24000   // row offset of shared region in H/ACT/O16 buffers

typedef unsigned short u16;
typedef unsigned int u32;
typedef __attribute__((ext_vector_type(4))) float f32x4;
typedef __attribute__((ext_vector_type(8))) short short8;
typedef __attribute__((ext_vector_type(4))) u16 u16x4;
typedef __attribute__((ext_vector_type(8))) u16 u16x8;

__device__ __forceinline__ u16 f2bf(float f) {
  u32 u = __builtin_bit_cast(u32, f);
  return (u16)((u + 0x7fffu + ((u >> 16) & 1u)) >> 16);
}
__device__ __forceinline__ float bf2f(u16 h) {
  return __builtin_bit_cast(float, (u32)h << 16);
}

__device__ __forceinline__ void gload_lds16(const void* g, void* l) {
  __builtin_amdgcn_global_load_lds((const __attribute__((address_space(1))) u32*)g,
                                   (__attribute__((address_space(3))) u32*)l, 16, 0, 0);
}

// ---------------- weight f32 -> bf16 ----------------
__global__ __launch_bounds__(256) void cvt_bf16_kernel(const float* __restrict__ in,
                                                       u16* __restrict__ out, int n4) {
  const int i = blockIdx.x * 256 + threadIdx.x;
  if (i >= n4) return;
  f32x4 v = ((const f32x4*)in)[i];
  u16x4 o = { f2bf(v.x), f2bf(v.y), f2bf(v.z), f2bf(v.w) };
  ((u16x4*)out)[i] = o;
}

// ---------------- fused pre-LN + router: ONE WAVE PER TOKEN ----------------
__global__ __launch_bounds__(256) void ln_router_kernel(
    const float* __restrict__ x, const float* __restrict__ gamma, const float* __restrict__ beta,
    const float* __restrict__ rw, const float* __restrict__ rb,
    u16* __restrict__ nx, int* __restrict__ tok_e, float* __restrict__ tok_w,
    int* __restrict__ count) {
  const int t = blockIdx.x * 4 + (threadIdx.x >> 6);
  const int lane = threadIdx.x & 63;
  const f32x4* xrow = (const f32x4*)(x + (size_t)t * DIN);

  f32x4 xv[10];
  float s = 0.f, s2 = 0.f;
#pragma unroll
  for (int c = 0; c < 10; ++c) {
    xv[c] = xrow[c * 64 + lane];
#pragma unroll
    for (int i = 0; i < 4; ++i) { s += xv[c][i]; s2 += xv[c][i] * xv[c][i]; }
  }
#pragma unroll
  for (int off = 32; off > 0; off >>= 1) {
    s += __shfl_xor(s, off);
    s2 += __shfl_xor(s2, off);
  }
  const float mean = s * (1.0f / DIN);
  const float var = s2 * (1.0f / DIN) - mean * mean;
  const float rstd = rsqrtf(var + 1e-6f);

  u16* nxrow = nx + (size_t)t * DIN;
#pragma unroll
  for (int c = 0; c < 10; ++c) {
    f32x4 g = ((const f32x4*)gamma)[c * 64 + lane];
    f32x4 b = ((const f32x4*)beta)[c * 64 + lane];
    xv[c] = (xv[c] - mean) * rstd * g + b;
    u16x4 p = { f2bf(xv[c].x), f2bf(xv[c].y), f2bf(xv[c].z), f2bf(xv[c].w) };
    ((u16x4*)nxrow)[c * 64 + lane] = p;
  }

  float lp[NEXP];
#pragma unroll
  for (int e = 0; e < NEXP; ++e) {
    const f32x4* rwe = (const f32x4*)(rw + (size_t)e * DIN);
    float acc = 0.f;
#pragma unroll
    for (int c = 0; c < 10; ++c) {
      f32x4 r = rwe[c * 64 + lane];
      acc += xv[c].x * r.x + xv[c].y * r.y + xv[c].z * r.z + xv[c].w * r.w;
    }
    lp[e] = acc;
  }
#pragma unroll
  for (int e = 0; e < NEXP; ++e)
#pragma unroll
    for (int off = 32; off > 0; off >>= 1) lp[e] += __shfl_xor(lp[e], off);

  if (lane == 0) {
    float lg[NEXP];
#pragma unroll
    for (int e = 0; e < NEXP; ++e) lg[e] = lp[e] + rb[e];
    float mx = lg[0];
#pragma unroll
    for (int e = 1; e < NEXP; ++e) mx = fmaxf(mx, lg[e]);
    float p[NEXP], ps = 0.f;
#pragma unroll
    for (int e = 0; e < NEXP; ++e) { p[e] = expf(lg[e] - mx); ps += p[e]; }
    int i0 = 0;
#pragma unroll
    for (int e = 1; e < NEXP; ++e) if (p[e] > p[i0]) i0 = e;
    int i1 = (i0 == 0) ? 1 : 0;
#pragma unroll
    for (int e = 0; e < NEXP; ++e) if (e != i0 && p[e] > p[i1]) i1 = e;
    float w0 = p[i0] / ps, w1 = p[i1] / ps;
    const float inv = 1.0f / (w0 + w1 + 1e-20f);
    w0 *= inv; w1 *= inv;
    tok_e[2 * t] = i0; tok_e[2 * t + 1] = i1;
    tok_w[2 * t] = w0; tok_w[2 * t + 1] = w1;
    atomicAdd(&count[i0 * 32], 1);
    atomicAdd(&count[i1 * 32], 1);
  }
}

__global__ void prefix_kernel(const int* __restrict__ count, int* __restrict__ prefix) {
  if (threadIdx.x == 0) {
    int acc = 0;
    for (int e = 0; e < NEXP; ++e) { prefix[e] = acc; acc += count[e * 32]; }
  }
}

__global__ __launch_bounds__(256) void assign_kernel(
    const int* __restrict__ tok_e, const float* __restrict__ tok_w, const int* __restrict__ prefix,
    int* __restrict__ cursor, int* __restrict__ slot_token, float* __restrict__ slot_w,
    int* __restrict__ token_slot) {
  const int t = blockIdx.x * 256 + threadIdx.x;
  if (t >= T_TOK) return;
#pragma unroll
  for (int k = 0; k < 2; ++k) {
    const int e = tok_e[2 * t + k];
    const int pos = atomicAdd(&cursor[e * 32], 1);
    const int sl = prefix[e] + pos;
    slot_token[sl] = t;
    slot_w[sl] = tok_w[2 * t + k];
    token_slot[2 * t + k] = sl;
  }
}

// ---------------- unified MoE GEMM: 9 "experts" (8 routed + shared) ---------
// PHASE 1: A0=nx[12000,2560], B=(e<8? ew12[e] : w12s) [1024,2560], C=H rows
//          {e<8: slot rows 0..24000 (gather nx via slot_token); e==8: SHBASE+t}
// PHASE 2: A0=ACT[36000,512],  B=(e<8? ew3[e] : w3s) [2048,512],  C=O16 rows
//          same row map; e<8 stores scaled by slot_w.
// Block remap: bijective XCD-chunked (m204) over live tile count, x-inner.
template <int PHASE>
__global__ __launch_bounds__(256, 2) void gemm_moe(
    const u16* __restrict__ A0, const u16* __restrict__ Bsh, const u16* __restrict__ Bex,
    u16* __restrict__ C,
    const int* __restrict__ cnt32, const int* __restrict__ prefix,
    const int* __restrict__ slot_token, const float* __restrict__ slot_w) {
  constexpr int N = (PHASE == 1) ? 1024 : 2048;
  constexpr int K = (PHASE == 1) ? 2560 : 512;
  constexpr int NX = N / 128;

  __shared__ u16 ldsA[128 * 64];
  __shared__ u16 ldsB[128 * 64];

  // total active tiles (all experts + shared)
  int A_act = 0;
#pragma unroll
  for (int ee = 0; ee < 9; ++ee) {
    const int c = (ee == 8) ? MSH : cnt32[ee * 32];
    A_act += ((c + 127) >> 7) * NX;
  }
  const int bid = blockIdx.x;
  if (bid >= A_act) return;

  // m204 bijective XCD-chunk remap (hardware round-robins consecutive bids)
  const int xcd = bid & 7, rank = bid >> 3;
  const int q = A_act >> 3, r = A_act & 7;
  const int tile = (xcd < r ? xcd * (q + 1) : r * (q + 1) + (xcd - r) * q) + rank;

  // predicated expert-bin scan (no runtime-indexed arrays)
  int e = 8, local = 0, m_valid = MSH, row_off = 0;
  {
    int bacc = 0, found = 0;
#pragma unroll
    for (int ee = 0; ee < 9; ++ee) {
      const int c = (ee == 8) ? MSH : cnt32[ee * 32];
      const int w = ((c + 127) >> 7) * NX;
      if (!found && tile < bacc + w) {
        found = 1; e = ee; local = tile - bacc; m_valid = c;
        row_off = (ee == 8) ? 0 : prefix[ee];
      }
      bacc += w;
    }
  }
  const int ty = local / NX;
  const int tx = local % NX;
  const int crow_base = (e == 8) ? SHBASE : row_off;
  const u16* Bb = (e == 8) ? Bsh : Bex + (size_t)e * N * K;

  const int tid = threadIdx.x;
  const int lane = tid & 63;
  const int wid = tid >> 6;
  const int kseg = (lane & 7) * 8;

  const u16* aptr[4];
  const u16* bptr[4];
#pragma unroll
  for (int i = 0; i < 4; ++i) {
    const int rr = wid * 32 + i * 8 + (lane >> 3);
    int gr = ty * 128 + rr;
    gr = gr < m_valid ? gr : (m_valid - 1);
    int ar;
    if constexpr (PHASE == 1) ar = (e == 8) ? gr : slot_token[row_off + gr];
    else                      ar = crow_base + gr;
    aptr[i] = A0 + (size_t)ar * K;
    bptr[i] = Bb + (size_t)(tx * 128 + rr) * K;
  }

  const f32x4 zero = {0.f, 0.f, 0.f, 0.f};
  f32x4 acc[4][4];
#pragma unroll
  for (int m = 0; m < 4; ++m)
#pragma unroll
    for (int n = 0; n < 4; ++n) acc[m][n] = zero;

  const int wr = (wid >> 1) * 64;
  const int wc = (wid & 1) * 64;
  const int fr = lane & 15;
  const int fk = (lane >> 4) * 8;

  for (int k0 = 0; k0 < K; k0 += 64) {
#pragma unroll
    for (int i = 0; i < 4; ++i) {
      gload_lds16(aptr[i] + k0 + kseg, &ldsA[(wid * 4 + i) * 512]);
      gload_lds16(bptr[i] + k0 + kseg, &ldsB[(wid * 4 + i) * 512]);
    }
    __syncthreads();
#pragma unroll
    for (int kk = 0; kk < 2; ++kk) {
      short8 af[4], bfm[4];
      const int kb = kk * 32 + fk;
#pragma unroll
      for (int m = 0; m < 4; ++m)
        af[m] = *(const short8*)&ldsA[(wr + m * 16 + fr) * 64 + kb];
#pragma unroll
      for (int n = 0; n < 4; ++n)
        bfm[n] = *(const short8*)&ldsB[(wc + n * 16 + fr) * 64 + kb];
#pragma unroll
      for (int m = 0; m < 4; ++m)
#pragma unroll
        for (int n = 0; n < 4; ++n)
          acc[m][n] = __builtin_amdgcn_mfma_f32_16x16x32_bf16(af[m], bfm[n], acc[m][n], 0, 0, 0);
    }
    __syncthreads();
  }

  const int ccol = wc + (lane & 15);
#pragma unroll
  for (int m = 0; m < 4; ++m) {
#pragma unroll
    for (int i = 0; i < 4; ++i) {
      const int row = wr + m * 16 + (lane >> 4) * 4 + i;
      const int gr = ty * 128 + row;
      if (gr < m_valid) {
        float wscale = 1.0f;
        if constexpr (PHASE == 2) wscale = (e == 8) ? 1.0f : slot_w[row_off + gr];
        u16* crow = C + (size_t)(crow_base + gr) * N + tx * 128;
#pragma unroll
        for (int n = 0; n < 4; ++n) crow[ccol + n * 16] = f2bf(acc[m][n][i] * wscale);
      }
    }
  }
}

// ---------------- SwiGLU activation: h[*,1024] -> a[*,512] ----------------
__global__ __launch_bounds__(256) void act_kernel(const u16* __restrict__ h,
                                                  u16* __restrict__ a, int rows) {
  const int idx = blockIdx.x * 256 + threadIdx.x;
  if (idx >= rows * 64) return;
  const int r = idx >> 6;
  const int c = (idx & 63) * 8;
  u16x8 g8 = *(const u16x8*)&h[(size_t)r * 1024 + c];
  u16x8 v8 = *(const u16x8*)&h[(size_t)r * 1024 + 512 + c];
  u16x8 o;
#pragma unroll
  for (int i = 0; i < 8; ++i) {
    const float g = bf2f(g8[i]);
    const float v = bf2f(v8[i]);
    const float sig = 1.0f / (1.0f + __expf(-g));
    o[i] = f2bf(g * sig * v);
  }
  *(u16x8*)&a[(size_t)r * 512 + c] = o;
}

// ---------------- final: out = LN(O16[SHBASE+t] + O16[s0] + O16[s1]) -------
__global__ __launch_bounds__(256) void final_ln_kernel(
    const u16* __restrict__ O16, const int* __restrict__ token_slot,
    const float* __restrict__ gamma, const float* __restrict__ beta, float* __restrict__ out) {
  const int t = blockIdx.x;
  const int tid = threadIdx.x;
  const int lane = tid & 63;
  const int wv = tid >> 6;
  const int s0 = token_slot[2 * t], s1 = token_slot[2 * t + 1];
  const int c = tid * 8;
  u16x8 a8 = *(const u16x8*)&O16[(size_t)(SHBASE + t) * DOUT + c];
  u16x8 b8 = *(const u16x8*)&O16[(size_t)s0 * DOUT + c];
  u16x8 c8 = *(const u16x8*)&O16[(size_t)s1 * DOUT + c];
  float v[8];
  float s = 0.f, s2 = 0.f;
#pragma unroll
  for (int i = 0; i < 8; ++i) {
    v[i] = bf2f(a8[i]) + bf2f(b8[i]) + bf2f(c8[i]);
    s += v[i];
    s2 += v[i] * v[i];
  }
#pragma unroll
  for (int off = 32; off > 0; off >>= 1) {
    s += __shfl_xor(s, off);
    s2 += __shfl_xor(s2, off);
  }
  __shared__ float red[4][2];
  if (lane == 0) { red[wv][0] = s; red[wv][1] = s2; }
  __syncthreads();
  const float S = red[0][0] + red[1][0] + red[2][0] + red[3][0];
  const float S2 = red[0][1] + red[1][1] + red[2][1] + red[3][1];
  const float mean = S * (1.0f / DOUT);
  const float var = S2 * (1.0f / DOUT) - mean * mean;
  const float rstd = rsqrtf(var + 1e-6f);
  f32x4 g0 = ((const f32x4*)gamma)[tid * 2], g1 = ((const f32x4*)gamma)[tid * 2 + 1];
  f32x4 be0 = ((const f32x4*)beta)[tid * 2], be1 = ((const f32x4*)beta)[tid * 2 + 1];
  f32x4 o0, o1;
#pragma unroll
  for (int i = 0; i < 4; ++i) {
    o0[i] = (v[i] - mean) * rstd * g0[i] + be0[i];
    o1[i] = (v[4 + i] - mean) * rstd * g1[i] + be1[i];
  }
  f32x4* orow = (f32x4*)(out + (size_t)t * DOUT);
  orow[tid * 2] = o0;
  orow[tid * 2 + 1] = o1;
}

extern "C" void kernel_launch(void* const* d_in, const int* in_sizes, int n_in,
                              void* d_out, int out_size, void* d_ws, size_t ws_size,
                              hipStream_t stream) {
  (void)in_sizes; (void)n_in; (void)out_size; (void)ws_size;
  const float* x = (const float*)d_in[0];
  const float* ln_pre_g = (const float*)d_in[1];
  const float* ln_pre_b = (const float*)d_in[2];
  const float* router_w = (const float*)d_in[3];
  const float* router_b = (const float*)d_in[4];
  const float* shared_w12 = (const float*)d_in[5];
  const float* shared_w3 = (const float*)d_in[6];
  const float* experts_w12 = (const float*)d_in[7];
  const float* experts_w3 = (const float*)d_in[8];
  const float* ln_post_g = (const float*)d_in[9];
  const float* ln_post_b = (const float*)d_in[10];
  float* out = (float*)d_out;

  size_t off = 0;
  char* ws = (char*)d_ws;
  auto take = [&](size_t bytes) -> void* {
    void* p = ws + off;
    off += (bytes + 255) & ~(size_t)255;
    return p;
  };
  u16* w12s = (u16*)take((size_t)1024 * 2560 * 2);
  u16* w3s  = (u16*)take((size_t)2048 * 512 * 2);
  u16* ew12 = (u16*)take((size_t)NEXP * 1024 * 2560 * 2);
  u16* ew3  = (u16*)take((size_t)NEXP * 2048 * 512 * 2);
  u16* nx   = (u16*)take((size_t)T_TOK * DIN * 2);
  u16* act  = (u16*)take((size_t)36000 * DH * 2);
  u16* O16  = (u16*)take((size_t)36000 * DOUT * 2);
  u16* H    = O16;   // alias: H[36000,1024] dead before O16 written
  int* tok_e = (int*)take(NSLOT * 4);
  float* tok_w = (float*)take(NSLOT * 4);
  int* slot_token = (int*)take(NSLOT * 4);
  float* slot_w = (float*)take(NSLOT * 4);
  int* token_slot = (int*)take(NSLOT * 4);
  int* cnt = (int*)take(3 * 8 * 32 * 4);   // count[8*32] | cursor[8*32] | prefix[8]
  int* cursor = cnt + 8 * 32;
  int* prefix = cnt + 2 * 8 * 32;

  hipMemsetAsync(cnt, 0, 3 * 8 * 32 * 4, stream);

  cvt_bf16_kernel<<<(1024 * 2560 / 4 + 255) / 256, 256, 0, stream>>>(shared_w12, w12s, 1024 * 2560 / 4);
  cvt_bf16_kernel<<<(2048 * 512 / 4 + 255) / 256, 256, 0, stream>>>(shared_w3, w3s, 2048 * 512 / 4);
  cvt_bf16_kernel<<<(NEXP * 1024 * 2560 / 4 + 255) / 256, 256, 0, stream>>>(experts_w12, ew12, NEXP * 1024 * 2560 / 4);
  cvt_bf16_kernel<<<(NEXP * 2048 * 512 / 4 + 255) / 256, 256, 0, stream>>>(experts_w3, ew3, NEXP * 2048 * 512 / 4);

  ln_router_kernel<<<T_TOK / 4, 256, 0, stream>>>(x, ln_pre_g, ln_pre_b, router_w, router_b,
                                                  nx, tok_e, tok_w, cnt);
  prefix_kernel<<<1, 64, 0, stream>>>(cnt, prefix);
  assign_kernel<<<(T_TOK + 255) / 256, 256, 0, stream>>>(tok_e, tok_w, prefix, cursor,
                                                         slot_token, slot_w, token_slot);

  // FFN1 (routed experts + shared), FFN2 likewise
  // max tiles: (floor(24000/128)+8 + 94) * NX
  gemm_moe<1><<<(187 + 8 + 94) * 8, 256, 0, stream>>>(nx, w12s, ew12, H,
                                                      cnt, prefix, slot_token, slot_w);
  act_kernel<<<36000 * 64 / 256, 256, 0, stream>>>(H, act, 36000);
  gemm_moe<2><<<(187 + 8 + 94) * 16, 256, 0, stream>>>(act, w3s, ew3, O16,
                                                       cnt, prefix, slot_token, slot_w);

  final_ln_kernel<<<T_TOK, 256, 0, stream>>>(O16, token_slot, ln_post_g, ln_post_b, out);
}

// Round 4
// 607.194 us; speedup vs baseline: 1.5741x; 1.0657x over previous
//
#include <hip/hip_runtime.h>

#define T_TOK 12000
#define NSLOT 24000
#define DIN 2560
#define DH 512
#define DOUT 2048
#define NEXP 8
#define MSH 12000
#define SHBASE 24000   // row offset of shared region in H/ACT/O16 buffers

typedef unsigned short u16;
typedef unsigned int u32;
typedef __attribute__((ext_vector_type(4))) float f32x4;
typedef __attribute__((ext_vector_type(8))) short short8;
typedef __attribute__((ext_vector_type(4))) u16 u16x4;
typedef __attribute__((ext_vector_type(8))) u16 u16x8;

__device__ __forceinline__ u16 f2bf(float f) {
  u32 u = __builtin_bit_cast(u32, f);
  return (u16)((u + 0x7fffu + ((u >> 16) & 1u)) >> 16);
}
__device__ __forceinline__ float bf2f(u16 h) {
  return __builtin_bit_cast(float, (u32)h << 16);
}

__device__ __forceinline__ void gload_lds16(const void* g, void* l) {
  __builtin_amdgcn_global_load_lds((const __attribute__((address_space(1))) u32*)g,
                                   (__attribute__((address_space(3))) u32*)l, 16, 0, 0);
}

// ---------------- weight f32 -> bf16 ----------------
__global__ __launch_bounds__(256) void cvt_bf16_kernel(const float* __restrict__ in,
                                                       u16* __restrict__ out, int n4) {
  const int i = blockIdx.x * 256 + threadIdx.x;
  if (i >= n4) return;
  f32x4 v = ((const f32x4*)in)[i];
  u16x4 o = { f2bf(v.x), f2bf(v.y), f2bf(v.z), f2bf(v.w) };
  ((u16x4*)out)[i] = o;
}

// ---------------- fused pre-LN + router: ONE WAVE PER TOKEN ----------------
__global__ __launch_bounds__(256) void ln_router_kernel(
    const float* __restrict__ x, const float* __restrict__ gamma, const float* __restrict__ beta,
    const float* __restrict__ rw, const float* __restrict__ rb,
    u16* __restrict__ nx, int* __restrict__ tok_e, float* __restrict__ tok_w,
    int* __restrict__ count) {
  const int t = blockIdx.x * 4 + (threadIdx.x >> 6);
  const int lane = threadIdx.x & 63;
  const f32x4* xrow = (const f32x4*)(x + (size_t)t * DIN);

  f32x4 xv[10];
  float s = 0.f, s2 = 0.f;
#pragma unroll
  for (int c = 0; c < 10; ++c) {
    xv[c] = xrow[c * 64 + lane];
#pragma unroll
    for (int i = 0; i < 4; ++i) { s += xv[c][i]; s2 += xv[c][i] * xv[c][i]; }
  }
#pragma unroll
  for (int off = 32; off > 0; off >>= 1) {
    s += __shfl_xor(s, off);
    s2 += __shfl_xor(s2, off);
  }
  const float mean = s * (1.0f / DIN);
  const float var = s2 * (1.0f / DIN) - mean * mean;
  const float rstd = rsqrtf(var + 1e-6f);

  u16* nxrow = nx + (size_t)t * DIN;
#pragma unroll
  for (int c = 0; c < 10; ++c) {
    f32x4 g = ((const f32x4*)gamma)[c * 64 + lane];
    f32x4 b = ((const f32x4*)beta)[c * 64 + lane];
    xv[c] = (xv[c] - mean) * rstd * g + b;
    u16x4 p = { f2bf(xv[c].x), f2bf(xv[c].y), f2bf(xv[c].z), f2bf(xv[c].w) };
    ((u16x4*)nxrow)[c * 64 + lane] = p;
  }

  float lp[NEXP];
#pragma unroll
  for (int e = 0; e < NEXP; ++e) {
    const f32x4* rwe = (const f32x4*)(rw + (size_t)e * DIN);
    float acc = 0.f;
#pragma unroll
    for (int c = 0; c < 10; ++c) {
      f32x4 r = rwe[c * 64 + lane];
      acc += xv[c].x * r.x + xv[c].y * r.y + xv[c].z * r.z + xv[c].w * r.w;
    }
    lp[e] = acc;
  }
#pragma unroll
  for (int e = 0; e < NEXP; ++e)
#pragma unroll
    for (int off = 32; off > 0; off >>= 1) lp[e] += __shfl_xor(lp[e], off);

  if (lane == 0) {
    float lg[NEXP];
#pragma unroll
    for (int e = 0; e < NEXP; ++e) lg[e] = lp[e] + rb[e];
    float mx = lg[0];
#pragma unroll
    for (int e = 1; e < NEXP; ++e) mx = fmaxf(mx, lg[e]);
    float p[NEXP], ps = 0.f;
#pragma unroll
    for (int e = 0; e < NEXP; ++e) { p[e] = expf(lg[e] - mx); ps += p[e]; }
    int i0 = 0;
#pragma unroll
    for (int e = 1; e < NEXP; ++e) if (p[e] > p[i0]) i0 = e;
    int i1 = (i0 == 0) ? 1 : 0;
#pragma unroll
    for (int e = 0; e < NEXP; ++e) if (e != i0 && p[e] > p[i1]) i1 = e;
    float w0 = p[i0] / ps, w1 = p[i1] / ps;
    const float inv = 1.0f / (w0 + w1 + 1e-20f);
    w0 *= inv; w1 *= inv;
    tok_e[2 * t] = i0; tok_e[2 * t + 1] = i1;
    tok_w[2 * t] = w0; tok_w[2 * t + 1] = w1;
    atomicAdd(&count[i0 * 32], 1);
    atomicAdd(&count[i1 * 32], 1);
  }
}

__global__ void prefix_kernel(const int* __restrict__ count, int* __restrict__ prefix) {
  if (threadIdx.x == 0) {
    int acc = 0;
    for (int e = 0; e < NEXP; ++e) { prefix[e] = acc; acc += count[e * 32]; }
  }
}

__global__ __launch_bounds__(256) void assign_kernel(
    const int* __restrict__ tok_e, const float* __restrict__ tok_w, const int* __restrict__ prefix,
    int* __restrict__ cursor, int* __restrict__ slot_token, float* __restrict__ slot_w,
    int* __restrict__ token_slot) {
  const int t = blockIdx.x * 256 + threadIdx.x;
  if (t >= T_TOK) return;
#pragma unroll
  for (int k = 0; k < 2; ++k) {
    const int e = tok_e[2 * t + k];
    const int pos = atomicAdd(&cursor[e * 32], 1);
    const int sl = prefix[e] + pos;
    slot_token[sl] = t;
    slot_w[sl] = tok_w[2 * t + k];
    token_slot[2 * t + k] = sl;
  }
}

// ---------------- unified MoE GEMM: 9 "experts" (8 routed + shared) ---------
// LDS K-swizzle (rule #21 both-sides): LDS dest stays linear [128][64];
// the 16B k-slot is XOR'd with (row&7) on the GLOBAL source address at stage
// time and on the ds_read address at use time. Involution; kills the 16-way
// stride-128B bank conflict (residual 2-way = free, m136).
template <int PHASE>
__global__ __launch_bounds__(256, 2) void gemm_moe(
    const u16* __restrict__ A0, const u16* __restrict__ Bsh, const u16* __restrict__ Bex,
    u16* __restrict__ C,
    const int* __restrict__ cnt32, const int* __restrict__ prefix,
    const int* __restrict__ slot_token, const float* __restrict__ slot_w) {
  constexpr int N = (PHASE == 1) ? 1024 : 2048;
  constexpr int K = (PHASE == 1) ? 2560 : 512;
  constexpr int NX = N / 128;

  __shared__ u16 ldsA[128 * 64];
  __shared__ u16 ldsB[128 * 64];

  // total active tiles (all experts + shared)
  int A_act = 0;
#pragma unroll
  for (int ee = 0; ee < 9; ++ee) {
    const int c = (ee == 8) ? MSH : cnt32[ee * 32];
    A_act += ((c + 127) >> 7) * NX;
  }
  const int bid = blockIdx.x;
  if (bid >= A_act) return;

  // m204 bijective XCD-chunk remap (hardware round-robins consecutive bids)
  const int xcd = bid & 7, rank = bid >> 3;
  const int q = A_act >> 3, r = A_act & 7;
  const int tile = (xcd < r ? xcd * (q + 1) : r * (q + 1) + (xcd - r) * q) + rank;

  // predicated expert-bin scan (no runtime-indexed arrays)
  int e = 8, local = 0, m_valid = MSH, row_off = 0;
  {
    int bacc = 0, found = 0;
#pragma unroll
    for (int ee = 0; ee < 9; ++ee) {
      const int c = (ee == 8) ? MSH : cnt32[ee * 32];
      const int w = ((c + 127) >> 7) * NX;
      if (!found && tile < bacc + w) {
        found = 1; e = ee; local = tile - bacc; m_valid = c;
        row_off = (ee == 8) ? 0 : prefix[ee];
      }
      bacc += w;
    }
  }
  const int ty = local / NX;
  const int tx = local % NX;
  const int crow_base = (e == 8) ? SHBASE : row_off;
  const u16* Bb = (e == 8) ? Bsh : Bex + (size_t)e * N * K;

  const int tid = threadIdx.x;
  const int lane = tid & 63;
  const int wid = tid >> 6;
  // pre-swizzled global k-offset: staged row&7 == lane>>3 for every segment
  const int sk8 = ((lane & 7) ^ (lane >> 3)) * 8;

  const u16* aptr[4];
  const u16* bptr[4];
#pragma unroll
  for (int i = 0; i < 4; ++i) {
    const int rr = wid * 32 + i * 8 + (lane >> 3);
    int gr = ty * 128 + rr;
    gr = gr < m_valid ? gr : (m_valid - 1);
    int ar;
    if constexpr (PHASE == 1) ar = (e == 8) ? gr : slot_token[row_off + gr];
    else                      ar = crow_base + gr;
    aptr[i] = A0 + (size_t)ar * K;
    bptr[i] = Bb + (size_t)(tx * 128 + rr) * K;
  }

  const f32x4 zero = {0.f, 0.f, 0.f, 0.f};
  f32x4 acc[4][4];
#pragma unroll
  for (int m = 0; m < 4; ++m)
#pragma unroll
    for (int n = 0; n < 4; ++n) acc[m][n] = zero;

  const int wr = (wid >> 1) * 64;
  const int wc = (wid & 1) * 64;
  const int fr = lane & 15;
  const int fk = (lane >> 4) * 8;

  for (int k0 = 0; k0 < K; k0 += 64) {
#pragma unroll
    for (int i = 0; i < 4; ++i) {
      gload_lds16(aptr[i] + k0 + sk8, &ldsA[(wid * 4 + i) * 512]);
      gload_lds16(bptr[i] + k0 + sk8, &ldsB[(wid * 4 + i) * 512]);
    }
    __syncthreads();
#pragma unroll
    for (int kk = 0; kk < 2; ++kk) {
      short8 af[4], bfm[4];
      // fragment rows have row&7 == lane&7 for both A and B reads
      const int kbs = (kk * 32 + fk) ^ ((lane & 7) << 3);
#pragma unroll
      for (int m = 0; m < 4; ++m)
        af[m] = *(const short8*)&ldsA[(wr + m * 16 + fr) * 64 + kbs];
#pragma unroll
      for (int n = 0; n < 4; ++n)
        bfm[n] = *(const short8*)&ldsB[(wc + n * 16 + fr) * 64 + kbs];
#pragma unroll
      for (int m = 0; m < 4; ++m)
#pragma unroll
        for (int n = 0; n < 4; ++n)
          acc[m][n] = __builtin_amdgcn_mfma_f32_16x16x32_bf16(af[m], bfm[n], acc[m][n], 0, 0, 0);
    }
    __syncthreads();
  }

  const int ccol = wc + (lane & 15);
#pragma unroll
  for (int m = 0; m < 4; ++m) {
#pragma unroll
    for (int i = 0; i < 4; ++i) {
      const int row = wr + m * 16 + (lane >> 4) * 4 + i;
      const int gr = ty * 128 + row;
      if (gr < m_valid) {
        float wscale = 1.0f;
        if constexpr (PHASE == 2) wscale = (e == 8) ? 1.0f : slot_w[row_off + gr];
        u16* crow = C + (size_t)(crow_base + gr) * N + tx * 128;
#pragma unroll
        for (int n = 0; n < 4; ++n) crow[ccol + n * 16] = f2bf(acc[m][n][i] * wscale);
      }
    }
  }
}

// ---------------- SwiGLU activation: h[*,1024] -> a[*,512] ----------------
__global__ __launch_bounds__(256) void act_kernel(const u16* __restrict__ h,
                                                  u16* __restrict__ a, int rows) {
  const int idx = blockIdx.x * 256 + threadIdx.x;
  if (idx >= rows * 64) return;
  const int r = idx >> 6;
  const int c = (idx & 63) * 8;
  u16x8 g8 = *(const u16x8*)&h[(size_t)r * 1024 + c];
  u16x8 v8 = *(const u16x8*)&h[(size_t)r * 1024 + 512 + c];
  u16x8 o;
#pragma unroll
  for (int i = 0; i < 8; ++i) {
    const float g = bf2f(g8[i]);
    const float v = bf2f(v8[i]);
    const float sig = 1.0f / (1.0f + __expf(-g));
    o[i] = f2bf(g * sig * v);
  }
  *(u16x8*)&a[(size_t)r * 512 + c] = o;
}

// ---------------- final: out = LN(O16[SHBASE+t] + O16[s0] + O16[s1]) -------
__global__ __launch_bounds__(256) void final_ln_kernel(
    const u16* __restrict__ O16, const int* __restrict__ token_slot,
    const float* __restrict__ gamma, const float* __restrict__ beta, float* __restrict__ out) {
  const int t = blockIdx.x;
  const int tid = threadIdx.x;
  const int lane = tid & 63;
  const int wv = tid >> 6;
  const int s0 = token_slot[2 * t], s1 = token_slot[2 * t + 1];
  const int c = tid * 8;
  u16x8 a8 = *(const u16x8*)&O16[(size_t)(SHBASE + t) * DOUT + c];
  u16x8 b8 = *(const u16x8*)&O16[(size_t)s0 * DOUT + c];
  u16x8 c8 = *(const u16x8*)&O16[(size_t)s1 * DOUT + c];
  float v[8];
  float s = 0.f, s2 = 0.f;
#pragma unroll
  for (int i = 0; i < 8; ++i) {
    v[i] = bf2f(a8[i]) + bf2f(b8[i]) + bf2f(c8[i]);
    s += v[i];
    s2 += v[i] * v[i];
  }
#pragma unroll
  for (int off = 32; off > 0; off >>= 1) {
    s += __shfl_xor(s, off);
    s2 += __shfl_xor(s2, off);
  }
  __shared__ float red[4][2];
  if (lane == 0) { red[wv][0] = s; red[wv][1] = s2; }
  __syncthreads();
  const float S = red[0][0] + red[1][0] + red[2][0] + red[3][0];
  const float S2 = red[0][1] + red[1][1] + red[2][1] + red[3][1];
  const float mean = S * (1.0f / DOUT);
  const float var = S2 * (1.0f / DOUT) - mean * mean;
  const float rstd = rsqrtf(var + 1e-6f);
  f32x4 g0 = ((const f32x4*)gamma)[tid * 2], g1 = ((const f32x4*)gamma)[tid * 2 + 1];
  f32x4 be0 = ((const f32x4*)beta)[tid * 2], be1 = ((const f32x4*)beta)[tid * 2 + 1];
  f32x4 o0, o1;
#pragma unroll
  for (int i = 0; i < 4; ++i) {
    o0[i] = (v[i] - mean) * rstd * g0[i] + be0[i];
    o1[i] = (v[4 + i] - mean) * rstd * g1[i] + be1[i];
  }
  f32x4* orow = (f32x4*)(out + (size_t)t * DOUT);
  orow[tid * 2] = o0;
  orow[tid * 2 + 1] = o1;
}

extern "C" void kernel_launch(void* const* d_in, const int* in_sizes, int n_in,
                              void* d_out, int out_size, void* d_ws, size_t ws_size,
                              hipStream_t stream) {
  (void)in_sizes; (void)n_in; (void)out_size; (void)ws_size;
  const float* x = (const float*)d_in[0];
  const float* ln_pre_g = (const float*)d_in[1];
  const float* ln_pre_b = (const float*)d_in[2];
  const float* router_w = (const float*)d_in[3];
  const float* router_b = (const float*)d_in[4];
  const float* shared_w12 = (const float*)d_in[5];
  const float* shared_w3 = (const float*)d_in[6];
  const float* experts_w12 = (const float*)d_in[7];
  const float* experts_w3 = (const float*)d_in[8];
  const float* ln_post_g = (const float*)d_in[9];
  const float* ln_post_b = (const float*)d_in[10];
  float* out = (float*)d_out;

  size_t off = 0;
  char* ws = (char*)d_ws;
  auto take = [&](size_t bytes) -> void* {
    void* p = ws + off;
    off += (bytes + 255) & ~(size_t)255;
    return p;
  };
  u16* w12s = (u16*)take((size_t)1024 * 2560 * 2);
  u16* w3s  = (u16*)take((size_t)2048 * 512 * 2);
  u16* ew12 = (u16*)take((size_t)NEXP * 1024 * 2560 * 2);
  u16* ew3  = (u16*)take((size_t)NEXP * 2048 * 512 * 2);
  u16* nx   = (u16*)take((size_t)T_TOK * DIN * 2);
  u16* act  = (u16*)take((size_t)36000 * DH * 2);
  u16* O16  = (u16*)take((size_t)36000 * DOUT * 2);
  u16* H    = O16;   // alias: H[36000,1024] dead before O16 written
  int* tok_e = (int*)take(NSLOT * 4);
  float* tok_w = (float*)take(NSLOT * 4);
  int* slot_token = (int*)take(NSLOT * 4);
  float* slot_w = (float*)take(NSLOT * 4);
  int* token_slot = (int*)take(NSLOT * 4);
  int* cnt = (int*)take(3 * 8 * 32 * 4);   // count[8*32] | cursor[8*32] | prefix[8]
  int* cursor = cnt + 8 * 32;
  int* prefix = cnt + 2 * 8 * 32;

  hipMemsetAsync(cnt, 0, 3 * 8 * 32 * 4, stream);

  cvt_bf16_kernel<<<(1024 * 2560 / 4 + 255) / 256, 256, 0, stream>>>(shared_w12, w12s, 1024 * 2560 / 4);
  cvt_bf16_kernel<<<(2048 * 512 / 4 + 255) / 256, 256, 0, stream>>>(shared_w3, w3s, 2048 * 512 / 4);
  cvt_bf16_kernel<<<(NEXP * 1024 * 2560 / 4 + 255) / 256, 256, 0, stream>>>(experts_w12, ew12, NEXP * 1024 * 2560 / 4);
  cvt_bf16_kernel<<<(NEXP * 2048 * 512 / 4 + 255) / 256, 256, 0, stream>>>(experts_w3, ew3, NEXP * 2048 * 512 / 4);

  ln_router_kernel<<<T_TOK / 4, 256, 0, stream>>>(x, ln_pre_g, ln_pre_b, router_w, router_b,
                                                  nx, tok_e, tok_w, cnt);
  prefix_kernel<<<1, 64, 0, stream>>>(cnt, prefix);
  assign_kernel<<<(T_TOK + 255) / 256, 256, 0, stream>>>(tok_e, tok_w, prefix, cursor,
                                                         slot_token, slot_w, token_slot);

  // FFN1 (routed experts + shared), FFN2 likewise
  gemm_moe<1><<<(187 + 8 + 94) * 8, 256, 0, stream>>>(nx, w12s, ew12, H,
                                                      cnt, prefix, slot_token, slot_w);
  act_kernel<<<36000 * 64 / 256, 256, 0, stream>>>(H, act, 36000);
  gemm_moe<2><<<(187 + 8 + 94) * 16, 256, 0, stream>>>(act, w3s, ew3, O16,
                                                       cnt, prefix, slot_token, slot_w);

  final_ln_kernel<<<T_TOK, 256, 0, stream>>>(O16, token_slot, ln_post_g, ln_post_b, out);
}